// Round 14
// baseline (471.735 us; speedup 1.0000x reference)
//
#include <hip/hip_runtime.h>
#include <hip/hip_bf16.h>
#include <math.h>
#include <stdint.h>

#define LRA 0.2f

typedef __attribute__((ext_vector_type(8))) short bf16x8;
typedef __attribute__((ext_vector_type(4))) float f32x4;
typedef unsigned long long u64;

__device__ __forceinline__ unsigned short f2bf(float v) {
  union { __hip_bfloat16 b; unsigned short u; } c;
  c.b = __float2bfloat16(v);
  return c.u;
}
__device__ __forceinline__ float bf2f(unsigned short h) {
  union { float f; unsigned int u; } a; a.u = ((unsigned int)h) << 16;
  return a.f;
}
__device__ __forceinline__ float warp_sum(float v){
  #pragma unroll
  for (int s = 32; s; s >>= 1) v += __shfl_xor(v, s);
  return v;
}

// =============== adjacency -> bitmasks (once) ===============
__global__ __launch_bounds__(256) void k_mask(const int* __restrict__ adj, u64* __restrict__ mg){
  const int t = threadIdx.x, lane = t & 63, w = t >> 6, b = blockIdx.x;
  const int* adjb = adj + (size_t)b * 128 * 128;
  for (int i = w * 32; i < w * 32 + 32; ++i) {
    u64 b0 = __ballot(adjb[i * 128 + lane] > 0);
    u64 b1 = __ballot(adjb[i * 128 + 64 + lane] > 0);
    if (lane == 0) { mg[((size_t)b * 128 + i) * 2] = b0; mg[((size_t)b * 128 + i) * 2 + 1] = b1; }
  }
}

// =============== prep: W_heads -> fragment hi/lo (PER-HEAD 64-col padding) ===============
__global__ __launch_bounds__(64) void k_prep1(
    const float* __restrict__ Whw, unsigned short* __restrict__ BH, unsigned short* __restrict__ BL)
{
  const int kt = blockIdx.x, nt = blockIdx.y, l = threadIdx.x;
  const int n = nt * 16 + (l & 15), k0 = kt * 32 + (l >> 4) * 8;
  const int hd = n >> 6, j = n & 63;
  uint4 hv, lv;
  unsigned int* hp = (unsigned int*)&hv;
  unsigned int* lp = (unsigned int*)&lv;
  #pragma unroll
  for (int p = 0; p < 4; ++p) {
    unsigned short hh[2], ll[2];
    #pragma unroll
    for (int e = 0; e < 2; ++e) {
      const int k = k0 + p * 2 + e;
      const float v = (j < 60 && k < 133) ? Whw[((size_t)hd * 133 + k) * 60 + j] : 0.f;
      const unsigned short h = f2bf(v);
      hh[e] = h; ll[e] = f2bf(v - bf2f(h));
    }
    hp[p] = hh[0] | ((unsigned int)hh[1] << 16);
    lp[p] = ll[0] | ((unsigned int)ll[1] << 16);
  }
  const size_t off = (((size_t)(kt * 32 + nt)) * 64 + l) * 8;
  *(uint4*)&BH[off] = hv;
  *(uint4*)&BL[off] = lv;
}

// =============== prep: Wout -> fragment hi/lo (K = hd*60+cl, N padded 320) ===============
__global__ __launch_bounds__(64) void k_prep2(
    const float* __restrict__ W, unsigned short* __restrict__ BH, unsigned short* __restrict__ BL)
{
  const int kt = blockIdx.x, nt = blockIdx.y, l = threadIdx.x;
  const int n = nt * 16 + (l & 15), k0 = kt * 32 + (l >> 4) * 8;
  uint4 hv, lv;
  unsigned int* hp = (unsigned int*)&hv;
  unsigned int* lp = (unsigned int*)&lv;
  #pragma unroll
  for (int p = 0; p < 4; ++p) {
    unsigned short hh[2], ll[2];
    #pragma unroll
    for (int e = 0; e < 2; ++e) {
      const int k = k0 + p * 2 + e;
      const float v = (n < 300 && k < 480) ? W[(size_t)k * 300 + n] : 0.f;
      const unsigned short h = f2bf(v);
      hh[e] = h; ll[e] = f2bf(v - bf2f(h));
    }
    hp[p] = hh[0] | ((unsigned int)hh[1] << 16);
    lp[p] = ll[0] | ((unsigned int)ll[1] << 16);
  }
  const size_t off = (((size_t)(kt * 20 + nt)) * 64 + l) * 8;
  *(uint4*)&BH[off] = hv;
  *(uint4*)&BL[off] = lv;
}

// =============== GEMM1: Wh = x @ Bcat(per-head-64); frag-major store; s1/d1 ===============
// grid 2048: b=bid>>2, p=bid&3 (rows p*32..+31). 8 waves; wave w = head w, ntl 0..3.
// Chunk layout per b (131072 ushorts): head hd at hd*16384:
//   WhFragH [16][64][8] (8192), WhFragL at +8192.
__global__ __launch_bounds__(512) void k_gemm1(
    const float* __restrict__ x,
    const unsigned short* __restrict__ BH, const unsigned short* __restrict__ BL,
    const float* __restrict__ asrc, const float* __restrict__ adst,
    unsigned short* __restrict__ slabs, float* __restrict__ s1g, float* __restrict__ d1g)
{
  __shared__ unsigned short Ah[32][40], Al[32][40];
  __shared__ float asl[512], adl[512];
  const int t = threadIdx.x, lane = t & 63, w = t >> 6, r = lane & 15, g = lane >> 4;
  const int b = blockIdx.x >> 2, p = blockIdx.x & 3;
  const int row0 = p * 32;
  const float* xb = x + (size_t)b * 128 * 133;
  unsigned short* chunk = slabs + (size_t)b * 131072;

  { const int hd = t >> 6, j = t & 63;
    asl[t] = (j < 60) ? asrc[hd * 60 + j] : 0.f;
    adl[t] = (j < 60) ? adst[hd * 60 + j] : 0.f; }

  f32x4 acc[2][4];
  #pragma unroll
  for (int mt = 0; mt < 2; ++mt)
    #pragma unroll
    for (int ntl = 0; ntl < 4; ++ntl) acc[mt][ntl] = (f32x4){0.f,0.f,0.f,0.f};

  for (int kt = 0; kt < 5; ++kt) {
    if (t < 256) {
      const int row_l = t >> 3, sl = t & 7;
      const int k0 = kt * 32 + sl * 4;
      unsigned short hh[4], ll[4];
      #pragma unroll
      for (int e = 0; e < 4; ++e) {
        const int k = k0 + e;
        const float v = (k < 133) ? xb[(size_t)(row0 + row_l) * 133 + k] : 0.f;
        hh[e] = f2bf(v); ll[e] = f2bf(v - bf2f(hh[e]));
      }
      uint2 hv, lv;
      hv.x = hh[0] | ((unsigned int)hh[1] << 16); hv.y = hh[2] | ((unsigned int)hh[3] << 16);
      lv.x = ll[0] | ((unsigned int)ll[1] << 16); lv.y = ll[2] | ((unsigned int)ll[3] << 16);
      *(uint2*)&Ah[row_l][sl * 4] = hv;
      *(uint2*)&Al[row_l][sl * 4] = lv;
    }
    bf16x8 bh[4], bl[4];
    #pragma unroll
    for (int ntl = 0; ntl < 4; ++ntl) {
      const size_t off = (((size_t)(kt * 32 + w * 4 + ntl)) * 64 + lane) * 8;
      bh[ntl] = *(const bf16x8*)&BH[off];
      bl[ntl] = *(const bf16x8*)&BL[off];
    }
    __syncthreads();
    #pragma unroll
    for (int mt = 0; mt < 2; ++mt) {
      const int row_l = mt * 16 + r;
      const bf16x8 ah = *(const bf16x8*)&Ah[row_l][g * 8];
      const bf16x8 al = *(const bf16x8*)&Al[row_l][g * 8];
      #pragma unroll
      for (int ntl = 0; ntl < 4; ++ntl) {
        acc[mt][ntl] = __builtin_amdgcn_mfma_f32_16x16x32_bf16(ah, bh[ntl], acc[mt][ntl], 0,0,0);
        acc[mt][ntl] = __builtin_amdgcn_mfma_f32_16x16x32_bf16(al, bh[ntl], acc[mt][ntl], 0,0,0);
        acc[mt][ntl] = __builtin_amdgcn_mfma_f32_16x16x32_bf16(ah, bl[ntl], acc[mt][ntl], 0,0,0);
      }
    }
    __syncthreads();
  }
  // fragment-major store: 512B contiguous per wave per store instruction
  #pragma unroll
  for (int mt = 0; mt < 2; ++mt)
    #pragma unroll
    for (int ntl = 0; ntl < 4; ++ntl) {
      unsigned short hh[4], ll[4];
      #pragma unroll
      for (int q = 0; q < 4; ++q) {
        const float v = acc[mt][ntl][q];
        hh[q] = f2bf(v); ll[q] = f2bf(v - bf2f(hh[q]));
      }
      uint2 hv, lv;
      hv.x = hh[0] | ((unsigned int)hh[1] << 16); hv.y = hh[2] | ((unsigned int)hh[3] << 16);
      lv.x = ll[0] | ((unsigned int)ll[1] << 16); lv.y = ll[2] | ((unsigned int)ll[3] << 16);
      const int tile = (ntl << 2) | p;
      const int li = (mt * 2 + (g >> 1)) * 16 + r;
      const size_t off = (size_t)w * 16384 + ((size_t)tile * 64 + li) * 8 + (g & 1) * 4;
      *(uint2*)&chunk[off] = hv;
      *(uint2*)&chunk[off + 8192] = lv;
    }
  // s1/d1: wave w = head w (clean, no bucket split)
  #pragma unroll
  for (int mt = 0; mt < 2; ++mt) {
    #pragma unroll
    for (int q = 0; q < 4; ++q) {
      float sv = 0.f, dv = 0.f;
      #pragma unroll
      for (int ntl = 0; ntl < 4; ++ntl) {
        const float a = acc[mt][ntl][q];
        const int cc = w * 64 + ntl * 16 + r;
        sv += a * asl[cc]; dv += a * adl[cc];
      }
      #pragma unroll
      for (int s = 1; s <= 8; s <<= 1) { sv += __shfl_xor(sv, s); dv += __shfl_xor(dv, s); }
      if (r == 0) {
        const int row = row0 + mt * 16 + g * 4 + q;
        s1g[((size_t)b * 8 + w) * 128 + row] = sv;
        d1g[((size_t)b * 8 + w) * 128 + row] = dv;
      }
    }
  }
}

// ===== merged attention-fragment generator (shared by att1/att2) =====
__device__ __forceinline__ float make_att_frags(
    const float si, const u64 ma, const u64 mb2, const float* darr,
    const int g, bf16x8* pah, bf16x8* pal)
{
  const unsigned int mby[4] = {
    (unsigned int)(ma  >> (g * 8)) & 0xffu,
    (unsigned int)(ma  >> (32 + g * 8)) & 0xffu,
    (unsigned int)(mb2 >> (g * 8)) & 0xffu,
    (unsigned int)(mb2 >> (32 + g * 8)) & 0xffu };
  float ev[4][8];
  float mx = -3e38f;
  #pragma unroll
  for (int kt = 0; kt < 4; ++kt)
    #pragma unroll
    for (int e = 0; e < 8; ++e) {
      const int j = ((kt & 1) * 32) + ((kt >> 1) * 64) + g * 8 + e;
      float v = si + darr[j];
      v = fmaxf(v, LRA * v);
      const float vv = (mby[((kt & 1) << 1) | (kt >> 1)] & (1u << e)) ? v : -3e38f;
      ev[kt][e] = vv;
      mx = fmaxf(mx, vv);
    }
  mx = fmaxf(mx, __shfl_xor(mx, 16));
  mx = fmaxf(mx, __shfl_xor(mx, 32));
  float sum = 0.f;
  #pragma unroll
  for (int kt = 0; kt < 4; ++kt)
    #pragma unroll
    for (int e = 0; e < 8; ++e) {
      const float p = (ev[kt][e] > -1e37f) ? __expf(ev[kt][e] - mx) : 0.f;
      ev[kt][e] = p;
      sum += p;
    }
  sum += __shfl_xor(sum, 16);
  sum += __shfl_xor(sum, 32);
  #pragma unroll
  for (int kt = 0; kt < 4; ++kt) {
    const int ks = ((kt & 1) << 1) | (kt >> 1);
    union { unsigned int u[4]; bf16x8 v; } hw, lw;
    #pragma unroll
    for (int p2 = 0; p2 < 4; ++p2) {
      const float p0 = ev[ks][2 * p2], p1 = ev[ks][2 * p2 + 1];
      const unsigned short h0 = f2bf(p0), h1 = f2bf(p1);
      hw.u[p2] = h0 | ((unsigned int)h1 << 16);
      lw.u[p2] = f2bf(p0 - bf2f(h0)) | ((unsigned int)f2bf(p1 - bf2f(h1)) << 16);
    }
    pah[kt] = hw.v;
    pal[kt] = lw.v;
  }
  return 1.f / sum;
}

// =============== att1: per (b,head); identity-copy staging; h row-major in-place ===============
__global__ __launch_bounds__(256) void k_att1(
    unsigned short* __restrict__ slabs, const u64* __restrict__ mg,
    const float* __restrict__ s1g, const float* __restrict__ d1g)
{
  __shared__ unsigned short Th[16][64][8], Tl[16][64][8];
  __shared__ float sarr[128], darr[128];
  __shared__ u64 mAr[128], mBr[128];
  const int t = threadIdx.x, lane = t & 63, w = t >> 6, r = lane & 15, g = lane >> 4;
  const int bid = blockIdx.x;
  const int lb = ((bid & 7) << 9) | (bid >> 3);
  const int b = lb >> 3, hd = lb & 7;
  const size_t sl = (size_t)b * 8 + hd;
  unsigned short* slot = slabs + (size_t)b * 131072 + hd * 16384;

  if (t < 128) {
    sarr[t] = s1g[sl * 128 + t];
    darr[t] = d1g[sl * 128 + t];
    mAr[t] = mg[((size_t)b * 128 + t) * 2];
    mBr[t] = mg[((size_t)b * 128 + t) * 2 + 1];
  }
  // identity staging: fully coalesced 16B/lane sequential
  unsigned short* ThF = &Th[0][0][0];
  unsigned short* TlF = &Tl[0][0][0];
  #pragma unroll
  for (int ii = 0; ii < 4; ++ii) {
    const int idx = t + ii * 256;
    *(uint4*)&ThF[idx * 8] = *(const uint4*)&slot[idx * 8];
    *(uint4*)&TlF[idx * 8] = *(const uint4*)&slot[8192 + idx * 8];
  }
  __syncthreads();
  bf16x8 pah[2][4], pal[2][4];
  float inv2[2];
  #pragma unroll
  for (int mt = 0; mt < 2; ++mt) {
    const int i = w * 32 + mt * 16 + r;
    inv2[mt] = make_att_frags(sarr[i], mAr[i], mBr[i], darr, g, pah[mt], pal[mt]);
  }
  f32x4 acc[2][4];
  #pragma unroll
  for (int mt = 0; mt < 2; ++mt)
    #pragma unroll
    for (int nt = 0; nt < 4; ++nt) acc[mt][nt] = (f32x4){0.f,0.f,0.f,0.f};
  #pragma unroll
  for (int kt = 0; kt < 4; ++kt)
    #pragma unroll
    for (int nt = 0; nt < 4; ++nt) {
      const bf16x8 bh = *(const bf16x8*)&Th[(nt << 2) | kt][lane][0];
      const bf16x8 bl = *(const bf16x8*)&Tl[(nt << 2) | kt][lane][0];
      #pragma unroll
      for (int mt = 0; mt < 2; ++mt) {
        acc[mt][nt] = __builtin_amdgcn_mfma_f32_16x16x32_bf16(pah[mt][kt], bh, acc[mt][nt], 0,0,0);
        acc[mt][nt] = __builtin_amdgcn_mfma_f32_16x16x32_bf16(pal[mt][kt], bh, acc[mt][nt], 0,0,0);
        acc[mt][nt] = __builtin_amdgcn_mfma_f32_16x16x32_bf16(pah[mt][kt], bl, acc[mt][nt], 0,0,0);
      }
    }
  // scale + ELU + h row-major store (in-place over this block's own slot)
  #pragma unroll
  for (int mt = 0; mt < 2; ++mt) {
    float sc[4];
    #pragma unroll
    for (int q = 0; q < 4; ++q) sc[q] = __shfl(inv2[mt], g * 4 + q);
    #pragma unroll
    for (int nt = 0; nt < 4; ++nt) {
      const int cc = nt * 16 + r;
      if (cc < 60) {
        #pragma unroll
        for (int q = 0; q < 4; ++q) {
          const int row = w * 32 + mt * 16 + g * 4 + q;
          float v = acc[mt][nt][q] * sc[q];
          v = v > 0.f ? v : __expf(v) - 1.f;
          const unsigned short h = f2bf(v);
          slot[row * 60 + cc] = h;
          slot[7680 + row * 60 + cc] = f2bf(v - bf2f(h));
        }
      }
    }
  }
}

// =============== GEMM2: Wo = h @ W_out; ONE block per b; Wo frag-major in-place; s2/d2 ===============
// 512 thr / 8 waves: wr = w>>1 (rows wr*32..+31, mt 0..1), wc = w&1 (cols wc*160, ntl 0..9).
__global__ __launch_bounds__(512) void k_gemm2(
    unsigned short* __restrict__ slabs,
    const unsigned short* __restrict__ BH, const unsigned short* __restrict__ BL,
    const float* __restrict__ aos, const float* __restrict__ aod,
    float* __restrict__ s2g, float* __restrict__ d2g)
{
  __shared__ unsigned short Ah[128][40], Al[128][40];
  __shared__ float aosl[320], aodl[320];
  __shared__ float sred[2][128], dred[2][128];
  const int t = threadIdx.x, lane = t & 63, w = t >> 6, r = lane & 15, g = lane >> 4;
  const int wr = w >> 1, wc = w & 1;
  const int b = blockIdx.x;
  unsigned short* chunk = slabs + (size_t)b * 131072;
  if (t < 320) { aosl[t] = t < 300 ? aos[t] : 0.f; aodl[t] = t < 300 ? aod[t] : 0.f; }

  f32x4 acc[2][10];
  #pragma unroll
  for (int mt = 0; mt < 2; ++mt)
    #pragma unroll
    for (int ntl = 0; ntl < 10; ++ntl) acc[mt][ntl] = (f32x4){0.f,0.f,0.f,0.f};

  for (int kt = 0; kt < 15; ++kt) {
    #pragma unroll
    for (int i = 0; i < 2; ++i) {
      const int idx = t + i * 512, row_l = idx >> 3, sl = idx & 7;
      const int k0 = kt * 32 + sl * 4;
      const int hd = k0 / 60, cl = k0 - hd * 60;
      const unsigned short* hb = chunk + hd * 16384 + row_l * 60 + cl;
      *(uint2*)&Ah[row_l][sl * 4] = *(const uint2*)hb;
      *(uint2*)&Al[row_l][sl * 4] = *(const uint2*)(hb + 7680);
    }
    __syncthreads();
    bf16x8 ah[2], al[2];
    #pragma unroll
    for (int mt = 0; mt < 2; ++mt) {
      const int row = wr * 32 + mt * 16 + r;
      ah[mt] = *(const bf16x8*)&Ah[row][g * 8];
      al[mt] = *(const bf16x8*)&Al[row][g * 8];
    }
    #pragma unroll
    for (int ntl = 0; ntl < 10; ++ntl) {
      const size_t off = (((size_t)(kt * 20 + wc * 10 + ntl)) * 64 + lane) * 8;
      const bf16x8 bh = *(const bf16x8*)&BH[off];
      const bf16x8 bl = *(const bf16x8*)&BL[off];
      #pragma unroll
      for (int mt = 0; mt < 2; ++mt) {
        acc[mt][ntl] = __builtin_amdgcn_mfma_f32_16x16x32_bf16(ah[mt], bh, acc[mt][ntl], 0,0,0);
        acc[mt][ntl] = __builtin_amdgcn_mfma_f32_16x16x32_bf16(al[mt], bh, acc[mt][ntl], 0,0,0);
        acc[mt][ntl] = __builtin_amdgcn_mfma_f32_16x16x32_bf16(ah[mt], bl, acc[mt][ntl], 0,0,0);
      }
    }
    __syncthreads();
  }
  // Wo fragment-major store (att2 layout): WoH at chunk[ch*8192+...], WoL at +40960
  #pragma unroll
  for (int mt = 0; mt < 2; ++mt)
    #pragma unroll
    for (int ntl = 0; ntl < 10; ++ntl) {
      const int cc = wc * 160 + ntl * 16 + r;
      unsigned short hh[4], ll[4];
      #pragma unroll
      for (int q = 0; q < 4; ++q) {
        const float v = (cc < 300) ? acc[mt][ntl][q] : 0.f;
        hh[q] = f2bf(v); ll[q] = f2bf(v - bf2f(hh[q]));
      }
      uint2 hv, lv;
      hv.x = hh[0] | ((unsigned int)hh[1] << 16); hv.y = hh[2] | ((unsigned int)hh[3] << 16);
      lv.x = ll[0] | ((unsigned int)ll[1] << 16); lv.y = ll[2] | ((unsigned int)ll[3] << 16);
      const int ch = cc >> 6;
      const int tile = (((cc >> 4) & 3) << 2) | wr;
      const int li = (mt * 2 + (g >> 1)) * 16 + r;
      const size_t off = (size_t)ch * 8192 + ((size_t)tile * 64 + li) * 8 + (g & 1) * 4;
      *(uint2*)&chunk[off] = hv;
      *(uint2*)&chunk[40960 + off] = lv;
    }
  // s2/d2 from live accumulators
  #pragma unroll
  for (int mt = 0; mt < 2; ++mt) {
    #pragma unroll
    for (int q = 0; q < 4; ++q) {
      float sv = 0.f, dv = 0.f;
      #pragma unroll
      for (int ntl = 0; ntl < 10; ++ntl) {
        const int cc = wc * 160 + ntl * 16 + r;
        const float a = acc[mt][ntl][q];
        sv += a * aosl[cc]; dv += a * aodl[cc];
      }
      #pragma unroll
      for (int s = 1; s <= 8; s <<= 1) { sv += __shfl_xor(sv, s); dv += __shfl_xor(dv, s); }
      if (r == 0) {
        const int row = wr * 32 + mt * 16 + g * 4 + q;
        sred[wc][row] = sv; dred[wc][row] = dv;
      }
    }
  }
  __syncthreads();
  if (t < 128) {
    s2g[(size_t)b * 128 + t] = sred[0][t] + sred[1][t];
    d2g[(size_t)b * 128 + t] = dred[0][t] + dred[1][t];
  }
}

// =============== att2 + elu + log_softmax(features) + mean (rank-1) ===============
__global__ __launch_bounds__(256) void k_att2(
    const unsigned short* __restrict__ slabs, const u64* __restrict__ mg,
    const float* __restrict__ s2g, const float* __restrict__ d2g,
    float* __restrict__ gat)
{
  __shared__ unsigned short Th[16][64][8], Tl[16][64][8];
  __shared__ float sarr[128], darr[128];
  __shared__ u64 mAr[128], mBr[128];
  __shared__ float colsum[304];
  __shared__ float srow[16];
  const int t = threadIdx.x, lane = t & 63, w = t >> 6, r = lane & 15, g = lane >> 4;
  const int b = blockIdx.x;
  const unsigned short* chunk = slabs + (size_t)b * 131072;

  if (t < 128) {
    sarr[t] = s2g[(size_t)b * 128 + t];
    darr[t] = d2g[(size_t)b * 128 + t];
    mAr[t] = mg[((size_t)b * 128 + t) * 2];
    mBr[t] = mg[((size_t)b * 128 + t) * 2 + 1];
  }
  for (int c = t; c < 304; c += 256) colsum[c] = 0.f;
  __syncthreads();
  bf16x8 pah[2][4], pal[2][4];
  float inv2[2];
  #pragma unroll
  for (int mt = 0; mt < 2; ++mt) {
    const int i = w * 32 + mt * 16 + r;
    inv2[mt] = make_att_frags(sarr[i], mAr[i], mBr[i], darr, g, pah[mt], pal[mt]);
  }
  float scq[2][4];
  #pragma unroll
  for (int mt = 0; mt < 2; ++mt)
    #pragma unroll
    for (int q = 0; q < 4; ++q) scq[mt][q] = __shfl(inv2[mt], g * 4 + q);

  float m8[2][4], l8[2][4];
  #pragma unroll
  for (int mt = 0; mt < 2; ++mt)
    #pragma unroll
    for (int q = 0; q < 4; ++q) { m8[mt][q] = -3e38f; l8[mt][q] = 0.f; }

  unsigned short* ThF = &Th[0][0][0];
  unsigned short* TlF = &Tl[0][0][0];
  for (int ch = 0; ch < 5; ++ch) {
    #pragma unroll
    for (int ii = 0; ii < 4; ++ii) {
      const int idx = t + ii * 256;
      *(uint4*)&ThF[idx * 8] = *(const uint4*)&chunk[(size_t)ch * 8192 + idx * 8];
      *(uint4*)&TlF[idx * 8] = *(const uint4*)&chunk[40960 + (size_t)ch * 8192 + idx * 8];
    }
    __syncthreads();
    f32x4 pacc[2][4];
    #pragma unroll
    for (int mt = 0; mt < 2; ++mt)
      #pragma unroll
      for (int nt = 0; nt < 4; ++nt) pacc[mt][nt] = (f32x4){0.f,0.f,0.f,0.f};
    #pragma unroll
    for (int kt = 0; kt < 4; ++kt)
      #pragma unroll
      for (int nt = 0; nt < 4; ++nt) {
        const bf16x8 bh = *(const bf16x8*)&Th[(nt << 2) | kt][lane][0];
        const bf16x8 bl = *(const bf16x8*)&Tl[(nt << 2) | kt][lane][0];
        #pragma unroll
        for (int mt = 0; mt < 2; ++mt) {
          pacc[mt][nt] = __builtin_amdgcn_mfma_f32_16x16x32_bf16(pah[mt][kt], bh, pacc[mt][nt], 0,0,0);
          pacc[mt][nt] = __builtin_amdgcn_mfma_f32_16x16x32_bf16(pal[mt][kt], bh, pacc[mt][nt], 0,0,0);
          pacc[mt][nt] = __builtin_amdgcn_mfma_f32_16x16x32_bf16(pah[mt][kt], bl, pacc[mt][nt], 0,0,0);
        }
      }
    float csA[4] = {0,0,0,0};
    #pragma unroll
    for (int mt = 0; mt < 2; ++mt) {
      float vq[4][4];
      #pragma unroll
      for (int nt = 0; nt < 4; ++nt) {
        const int cc = ch * 64 + nt * 16 + r;
        const bool cv = cc < 300;
        #pragma unroll
        for (int q = 0; q < 4; ++q) {
          float v = pacc[mt][nt][q] * scq[mt][q];
          v = v > 0.f ? v : __expf(v) - 1.f;
          vq[nt][q] = cv ? v : -3e38f;
          csA[nt] += cv ? v : 0.f;
        }
      }
      #pragma unroll
      for (int q = 0; q < 4; ++q) {
        float mx = fmaxf(fmaxf(vq[0][q], vq[1][q]), fmaxf(vq[2][q], vq[3][q]));
        mx = fmaxf(mx, __shfl_xor(mx, 1));
        mx = fmaxf(mx, __shfl_xor(mx, 2));
        mx = fmaxf(mx, __shfl_xor(mx, 4));
        mx = fmaxf(mx, __shfl_xor(mx, 8));
        const float nm = fmaxf(m8[mt][q], mx);
        float ps = __expf(vq[0][q]-nm) + __expf(vq[1][q]-nm) + __expf(vq[2][q]-nm) + __expf(vq[3][q]-nm);
        ps += __shfl_xor(ps, 1); ps += __shfl_xor(ps, 2);
        ps += __shfl_xor(ps, 4); ps += __shfl_xor(ps, 8);
        l8[mt][q] = l8[mt][q] * __expf(m8[mt][q] - nm) + ps;
        m8[mt][q] = nm;
      }
    }
    #pragma unroll
    for (int nt = 0; nt < 4; ++nt) {
      float cs = csA[nt];
      cs += __shfl_xor(cs, 16); cs += __shfl_xor(cs, 32);
      const int cc = ch * 64 + nt * 16 + r;
      if (g == 0 && cc < 300) atomicAdd(&colsum[cc], cs);
    }
    __syncthreads();
  }
  if (r == 0) {
    float sp = 0.f;
    #pragma unroll
    for (int mt = 0; mt < 2; ++mt)
      #pragma unroll
      for (int q = 0; q < 4; ++q) sp += m8[mt][q] + __logf(l8[mt][q]);
    srow[w * 4 + g] = sp;
  }
  __syncthreads();
  float S = 0.f;
  #pragma unroll
  for (int k = 0; k < 16; ++k) S += srow[k];
  for (int c = t; c < 300; c += 256)
    gat[(size_t)b * 300 + c] = (colsum[c] - S) * (1.f / 128.f);
}

// =============== split-K GEMM: P[sk][M][N] = A_chunk @ B_chunk (64x64 tile) ===============
__global__ __launch_bounds__(256) void k_gemm_sk(
    const float* __restrict__ A, const float* __restrict__ B,
    float* __restrict__ P, int M, int K, int N, int kpt)
{
  __shared__ unsigned short Ah[64][40], Al[64][40], Bh[64][40], Bl[64][40];
  const int t = threadIdx.x, lane = t & 63, w = t >> 6, r = lane & 15, g = lane >> 4;
  const int row0 = blockIdx.x * 64, col0 = blockIdx.y * 64;
  const int sk = blockIdx.z;
  const int k0 = sk * kpt * 32;
  const int kend = min(K, k0 + kpt * 32);

  f32x4 acc[4];
  #pragma unroll
  for (int nt = 0; nt < 4; ++nt) acc[nt] = (f32x4){0.f,0.f,0.f,0.f};

  for (int kt = k0; kt < kend; kt += 32) {
    #pragma unroll
    for (int ii = 0; ii < 2; ++ii) {
      const int idx = t + ii * 256, ar = idx >> 3, aq = (idx & 7) * 4, gk = kt + aq;
      const float* ap = &A[(size_t)(row0 + ar) * K + gk];
      float v0 = gk     < kend ? ap[0] : 0.f;
      float v1 = gk + 1 < kend ? ap[1] : 0.f;
      float v2 = gk + 2 < kend ? ap[2] : 0.f;
      float v3 = gk + 3 < kend ? ap[3] : 0.f;
      unsigned short h0=f2bf(v0),h1=f2bf(v1),h2=f2bf(v2),h3=f2bf(v3);
      *(unsigned int*)&Ah[ar][aq]   = h0 | ((unsigned int)h1 << 16);
      *(unsigned int*)&Ah[ar][aq+2] = h2 | ((unsigned int)h3 << 16);
      unsigned short l0=f2bf(v0-bf2f(h0)),l1=f2bf(v1-bf2f(h1)),l2=f2bf(v2-bf2f(h2)),l3=f2bf(v3-bf2f(h3));
      *(unsigned int*)&Al[ar][aq]   = l0 | ((unsigned int)l1 << 16);
      *(unsigned int*)&Al[ar][aq+2] = l2 | ((unsigned int)l3 << 16);
    }
    #pragma unroll
    for (int ii = 0; ii < 4; ++ii) {
      const int idx = t + ii * 256, n = idx & 63, kk = (idx >> 6) * 2;
      const int gn = col0 + n;
      float v0 = (gn < N && kt + kk     < kend) ? B[(size_t)(kt + kk) * N + gn] : 0.f;
      float v1 = (gn < N && kt + kk + 1 < kend) ? B[(size_t)(kt + kk + 1) * N + gn] : 0.f;
      unsigned short h0 = f2bf(v0), h1 = f2bf(v1);
      *(unsigned int*)&Bh[n][kk] = h0 | ((unsigned int)h1 << 16);
      unsigned short l0 = f2bf(v0 - bf2f(h0)), l1 = f2bf(v1 - bf2f(h1));
      *(unsigned int*)&Bl[n][kk] = l0 | ((unsigned int)l1 << 16);
    }
    __syncthreads();
    const bf16x8 ah  = *(const bf16x8*)&Ah[w * 16 + r][g * 8];
    const bf16x8 al2 = *(const bf16x8*)&Al[w * 16 + r][g * 8];
    #pragma unroll
    for (int nt = 0; nt < 4; ++nt) {
      const bf16x8 bh = *(const bf16x8*)&Bh[nt * 16 + r][g * 8];
      const bf16x8 bl = *(const bf16x8*)&Bl[nt * 16 + r][g * 8];
      acc[nt] = __builtin_amdgcn_mfma_f32_16x16x32_bf16(ah,  bh, acc[nt], 0,0,0);
      acc[nt] = __builtin_amdgcn_mfma_f32_16x16x32_bf16(al2, bh, acc[nt], 0,0,0);
      acc[nt] = __builtin_amdgcn_mfma_f32_16x16x32_bf16(ah,  bl, acc[nt], 0,0,0);
    }
    __syncthreads();
  }
  float* Pout = P + (size_t)sk * M * N;
  #pragma unroll
  for (int nt = 0; nt < 4; ++nt) {
    const int cc = col0 + nt * 16 + r;
    if (cc < N) {
      #pragma unroll
      for (int q = 0; q < 4; ++q)
        Pout[(size_t)(row0 + w * 16 + g * 4 + q) * N + cc] = acc[nt][q];
    }
  }
}

// =============== split-K reduce + bias + activation ===============
__global__ __launch_bounds__(256) void k_reduce(
    const float* __restrict__ P, const float* __restrict__ bias,
    float* __restrict__ C, int M, int N, int ldc, int nsk, int act)
{
  const int idx = blockIdx.x * 256 + threadIdx.x;
  if (idx >= M * N) return;
  const int row = idx / N, col = idx - row * N;
  float s = bias[col];
  for (int k = 0; k < nsk; ++k) s += P[(size_t)k * M * N + idx];
  if (act) s = fmaxf(s, 0.f);
  C[(size_t)row * ldc + col] = s;
}

// =============== final GEMV + sigmoid ===============
__global__ __launch_bounds__(512) void k_out(
    const float* __restrict__ z1, const float* __restrict__ w2,
    const float* __restrict__ b2, float* __restrict__ out)
{
  const int t = threadIdx.x, lane = t & 63, w = t >> 6;
  const int b = blockIdx.x * 8 + w;
  float p = 0.f;
  for (int k = lane; k < 300; k += 64) p += z1[(size_t)b * 300 + k] * w2[k];
  p = warp_sum(p);
  if (lane == 0) out[b] = 1.f / (1.f + __expf(-(p + b2[0])));
}

extern "C" void kernel_launch(void* const* d_in, const int* in_sizes, int n_in,
                              void* d_out, int out_size, void* d_ws, size_t ws_size,
                              hipStream_t stream)
{
  const float* x    = (const float*)d_in[0];
  const int*   adj  = (const int*)d_in[1];
  const float* fp   = (const float*)d_in[2];
  const float* Whw  = (const float*)d_in[3];
  const float* asrc = (const float*)d_in[4];
  const float* adst = (const float*)d_in[5];
  const float* Wout = (const float*)d_in[6];
  const float* aos  = (const float*)d_in[7];
  const float* aod  = (const float*)d_in[8];
  const float* fc1w = (const float*)d_in[9];
  const float* fc1b = (const float*)d_in[10];
  const float* fc2w = (const float*)d_in[11];
  const float* fc2b = (const float*)d_in[12];
  const float* fcgw = (const float*)d_in[13];
  const float* fcgb = (const float*)d_in[14];
  const float* fcfw = (const float*)d_in[15];
  const float* fcfb = (const float*)d_in[16];
  const float* f1w  = (const float*)d_in[17];
  const float* f1b  = (const float*)d_in[18];
  const float* f2w  = (const float*)d_in[19];
  const float* f2b  = (const float*)d_in[20];
  float* out = (float*)d_out;

  char* wsb = (char*)d_ws;
  unsigned short* slabs = (unsigned short*)wsb;                  // 512 x 262144 B = 134,217,728
  float* s1g = (float*)(wsb + 134217728);                        // 2 MB
  float* d1g = (float*)(wsb + 136314880);                        // 2 MB
  float* s2g = (float*)(wsb + 138412032);
  float* d2g = (float*)(wsb + 138674176);
  u64*   mgb = (u64*)  (wsb + 138936320);
  float* gatp = (float*)(wsb + 139984896);
  float* fpnp = (float*)(wsb + 140599296);
  float* f1buf = (float*)(wsb + 141213696);
  float* zb    = (float*)(wsb + 142262272);
  float* z1b   = (float*)(wsb + 143491072);
  float* P0 = (float*)(wsb + 144105472);
  float* P1 = (float*)(wsb + 150396928);
  float* P2 = (float*)(wsb + 152854528);
  float* P3 = (float*)(wsb + 154083328);
  float* P4 = (float*)(wsb + 155312128);
  unsigned short* Bf1H = (unsigned short*)(wsb + 157769728);     // 5x32x64x8 us
  unsigned short* Bf1L = (unsigned short*)(wsb + 157933568);
  unsigned short* Bf2H = (unsigned short*)(wsb + 158097408);     // 15x20x64x8 us
  unsigned short* Bf2L = (unsigned short*)(wsb + 158404608);

  k_prep1<<<dim3(5, 32), 64, 0, stream>>>(Whw, Bf1H, Bf1L);
  k_prep2<<<dim3(15, 20), 64, 0, stream>>>(Wout, Bf2H, Bf2L);
  k_mask <<<512, 256, 0, stream>>>(adj, mgb);
  k_gemm1<<<2048, 512, 0, stream>>>(x, Bf1H, Bf1L, asrc, adst, slabs, s1g, d1g);
  k_att1 <<<4096, 256, 0, stream>>>(slabs, mgb, s1g, d1g);
  k_gemm2<<<512, 512, 0, stream>>>(slabs, Bf2H, Bf2L, aos, aod, s2g, d2g);
  k_att2 <<<512, 256, 0, stream>>>(slabs, mgb, s2g, d2g, gatp);
  k_gemm_sk<<<dim3(8,8,6), 256, 0, stream>>>(fp, fc1w, P0, 512, 1489, 512, 8);
  k_reduce<<<1024, 256, 0, stream>>>(P0, fc1b, f1buf, 512, 512, 512, 6, 1);
  k_gemm_sk<<<dim3(8,5,4), 256, 0, stream>>>(f1buf, fc2w, P1, 512, 512, 300, 4);
  k_reduce<<<600, 256, 0, stream>>>(P1, fc2b, fpnp, 512, 300, 300, 4, 0);
  k_gemm_sk<<<dim3(8,5,2), 256, 0, stream>>>(gatp, fcgw, P2, 512, 300, 300, 5);
  k_gemm_sk<<<dim3(8,5,2), 256, 0, stream>>>(fpnp, fcfw, P3, 512, 300, 300, 5);
  k_reduce<<<600, 256, 0, stream>>>(P2, fcgb, zb, 512, 300, 600, 2, 1);
  k_reduce<<<600, 256, 0, stream>>>(P3, fcfb, zb + 300, 512, 300, 600, 2, 1);
  k_gemm_sk<<<dim3(8,5,4), 256, 0, stream>>>(zb, f1w, P4, 512, 600, 300, 5);
  k_reduce<<<600, 256, 0, stream>>>(P4, f1b, z1b, 512, 300, 300, 4, 1);
  k_out<<<64, 512, 0, stream>>>(z1b, f2w, f2b, out);
}

// Round 15
// 358.790 us; speedup vs baseline: 1.3148x; 1.3148x over previous
//
#include <hip/hip_runtime.h>
#include <hip/hip_bf16.h>
#include <math.h>
#include <stdint.h>

#define LRA 0.2f

typedef __attribute__((ext_vector_type(8))) short bf16x8;
typedef __attribute__((ext_vector_type(8))) unsigned short u16x8;
typedef __attribute__((ext_vector_type(4))) float f32x4;
typedef unsigned long long u64;

__device__ __forceinline__ unsigned short f2bf(float v) {
  union { __hip_bfloat16 b; unsigned short u; } c;
  c.b = __float2bfloat16(v);
  return c.u;
}
__device__ __forceinline__ float bf2f(unsigned short h) {
  union { float f; unsigned int u; } a; a.u = ((unsigned int)h) << 16;
  return a.f;
}
__device__ __forceinline__ float warp_sum(float v){
  #pragma unroll
  for (int s = 32; s; s >>= 1) v += __shfl_xor(v, s);
  return v;
}

// =============== adjacency -> bitmasks (once) ===============
__global__ __launch_bounds__(256) void k_mask(const int* __restrict__ adj, u64* __restrict__ mg){
  const int t = threadIdx.x, lane = t & 63, w = t >> 6, b = blockIdx.x;
  const int* adjb = adj + (size_t)b * 128 * 128;
  for (int i = w * 32; i < w * 32 + 32; ++i) {
    u64 b0 = __ballot(adjb[i * 128 + lane] > 0);
    u64 b1 = __ballot(adjb[i * 128 + 64 + lane] > 0);
    if (lane == 0) { mg[((size_t)b * 128 + i) * 2] = b0; mg[((size_t)b * 128 + i) * 2 + 1] = b1; }
  }
}

// =============== prep: W_heads -> fragment-layout hi/lo ===============
__global__ __launch_bounds__(64) void k_prep1(
    const float* __restrict__ Whw, unsigned short* __restrict__ BH, unsigned short* __restrict__ BL)
{
  const int kt = blockIdx.x, nt = blockIdx.y, l = threadIdx.x;
  const int n = nt * 16 + (l & 15), k0 = kt * 32 + (l >> 4) * 8;
  const int hd = n / 60, j = n - hd * 60;
  uint4 hv, lv;
  unsigned int* hp = (unsigned int*)&hv;
  unsigned int* lp = (unsigned int*)&lv;
  #pragma unroll
  for (int p = 0; p < 4; ++p) {
    unsigned short hh[2], ll[2];
    #pragma unroll
    for (int e = 0; e < 2; ++e) {
      const int k = k0 + p * 2 + e;
      const float v = (n < 480 && k < 133) ? Whw[((size_t)hd * 133 + k) * 60 + j] : 0.f;
      const unsigned short h = f2bf(v);
      hh[e] = h; ll[e] = f2bf(v - bf2f(h));
    }
    hp[p] = hh[0] | ((unsigned int)hh[1] << 16);
    lp[p] = ll[0] | ((unsigned int)ll[1] << 16);
  }
  const size_t off = (((size_t)(kt * 32 + nt)) * 64 + l) * 8;
  *(uint4*)&BH[off] = hv;
  *(uint4*)&BL[off] = lv;
}

// =============== prep: Wout -> fragment-layout hi/lo ===============
__global__ __launch_bounds__(64) void k_prep2(
    const float* __restrict__ W, unsigned short* __restrict__ BH, unsigned short* __restrict__ BL)
{
  const int kt = blockIdx.x, nt = blockIdx.y, l = threadIdx.x;
  const int n = nt * 16 + (l & 15), k0 = kt * 32 + (l >> 4) * 8;
  uint4 hv, lv;
  unsigned int* hp = (unsigned int*)&hv;
  unsigned int* lp = (unsigned int*)&lv;
  #pragma unroll
  for (int p = 0; p < 4; ++p) {
    unsigned short hh[2], ll[2];
    #pragma unroll
    for (int e = 0; e < 2; ++e) {
      const int k = k0 + p * 2 + e;
      const float v = (n < 300 && k < 480) ? W[(size_t)k * 300 + n] : 0.f;
      const unsigned short h = f2bf(v);
      hh[e] = h; ll[e] = f2bf(v - bf2f(h));
    }
    hp[p] = hh[0] | ((unsigned int)hh[1] << 16);
    lp[p] = ll[0] | ((unsigned int)ll[1] << 16);
  }
  const size_t off = (((size_t)(kt * 20 + nt)) * 64 + l) * 8;
  *(uint4*)&BH[off] = hv;
  *(uint4*)&BL[off] = lv;
}

// =============== GEMM1: Wh = x @ Bcat; 4 row-parts per batch ===============
// grid 2048: b = bid>>2, part p = bid&3 (rows p*32..p*32+31). 8 waves,
// wave w: nt w*4..w*4+3 (cols w*64..w*64+63). acc[2][4].
__global__ __launch_bounds__(512) void k_gemm1(
    const float* __restrict__ x,
    const unsigned short* __restrict__ BH, const unsigned short* __restrict__ BL,
    const float* __restrict__ asrc, const float* __restrict__ adst,
    unsigned int* __restrict__ buf1, float* __restrict__ s1g, float* __restrict__ d1g)
{
  __shared__ unsigned int Apk[32][32];           // packed hi|lo, 16B-slot XOR swizzle
  __shared__ float asl[512], adl[512];
  __shared__ float sp0[8][32], sp1[8][32], dp0[8][32], dp1[8][32];
  const int t = threadIdx.x, lane = t & 63, w = t >> 6, r = lane & 15, g = lane >> 4;
  const int b = blockIdx.x >> 2, p = blockIdx.x & 3;
  const int row0 = p * 32;
  const float* xb = x + (size_t)b * 128 * 133;
  unsigned int* slab = buf1 + (size_t)b * 61440;

  asl[t] = (t < 480) ? asrc[t] : 0.f;
  adl[t] = (t < 480) ? adst[t] : 0.f;

  f32x4 acc[2][4];
  #pragma unroll
  for (int mt = 0; mt < 2; ++mt)
    #pragma unroll
    for (int ntl = 0; ntl < 4; ++ntl) acc[mt][ntl] = (f32x4){0.f,0.f,0.f,0.f};

  for (int kt = 0; kt < 5; ++kt) {
    // stage A packed (32 rows x 32 k): 256 uint4 slots, threads t<256
    if (t < 256) {
      const int row_l = t >> 3, sl = t & 7;
      const int k0 = kt * 32 + sl * 4;
      uint4 pk;
      unsigned int* pp = (unsigned int*)&pk;
      #pragma unroll
      for (int e = 0; e < 4; ++e) {
        const int k = k0 + e;
        const float v = (k < 133) ? xb[(size_t)(row0 + row_l) * 133 + k] : 0.f;
        const unsigned short h = f2bf(v);
        pp[e] = ((unsigned int)h << 16) | f2bf(v - bf2f(h));
      }
      *(uint4*)&Apk[row_l][((sl ^ (row_l & 7)) << 2)] = pk;
    }
    bf16x8 bh[4], bl[4];
    #pragma unroll
    for (int ntl = 0; ntl < 4; ++ntl) {
      const int nt = w * 4 + ntl;
      const size_t off = (((size_t)(kt * 32 + nt)) * 64 + lane) * 8;
      bh[ntl] = *(const bf16x8*)&BH[off];
      bl[ntl] = *(const bf16x8*)&BL[off];
    }
    __syncthreads();
    #pragma unroll
    for (int mt = 0; mt < 2; ++mt) {
      const int row_l = mt * 16 + r, key = r & 7;
      const uint4 p0 = *(const uint4*)&Apk[row_l][(((2*g)   ^ key) << 2)];
      const uint4 p1 = *(const uint4*)&Apk[row_l][(((2*g+1) ^ key) << 2)];
      const unsigned int pw[8] = {p0.x,p0.y,p0.z,p0.w,p1.x,p1.y,p1.z,p1.w};
      bf16x8 ah, al;
      #pragma unroll
      for (int e = 0; e < 8; ++e) { ah[e] = (short)(pw[e] >> 16); al[e] = (short)(pw[e] & 0xffffu); }
      #pragma unroll
      for (int ntl = 0; ntl < 4; ++ntl) {
        acc[mt][ntl] = __builtin_amdgcn_mfma_f32_16x16x32_bf16(ah, bh[ntl], acc[mt][ntl], 0,0,0);
        acc[mt][ntl] = __builtin_amdgcn_mfma_f32_16x16x32_bf16(al, bh[ntl], acc[mt][ntl], 0,0,0);
        acc[mt][ntl] = __builtin_amdgcn_mfma_f32_16x16x32_bf16(ah, bl[ntl], acc[mt][ntl], 0,0,0);
      }
    }
    __syncthreads();
  }
  // WhT packed store (rows of this part only)
  #pragma unroll
  for (int mt = 0; mt < 2; ++mt)
    #pragma unroll
    for (int ntl = 0; ntl < 4; ++ntl) {
      const int cc = (w * 4 + ntl) * 16 + r;
      if (cc < 480) {
        const int hd = cc / 60, cl = cc - hd * 60;
        uint4 pv;
        unsigned int* pp = (unsigned int*)&pv;
        #pragma unroll
        for (int q = 0; q < 4; ++q) {
          const float v = acc[mt][ntl][q];
          const unsigned short h = f2bf(v);
          pp[q] = ((unsigned int)h << 16) | f2bf(v - bf2f(h));
        }
        *(uint4*)&slab[(size_t)hd * 7680 + (size_t)cl * 128 + row0 + mt * 16 + (g << 2)] = pv;
      }
    }
  // s1/d1: per-head bucket (cols-based logic unchanged; rows local)
  const int thr0 = 60 - 4 * w;
  #pragma unroll
  for (int mt = 0; mt < 2; ++mt) {
    #pragma unroll
    for (int q = 0; q < 4; ++q) {
      float s0 = 0.f, s1 = 0.f, d0 = 0.f, d1 = 0.f;
      #pragma unroll
      for (int ntl = 0; ntl < 4; ++ntl) {
        const int loc = ntl * 16 + r;
        const int cc = w * 64 + loc;
        const float a = acc[mt][ntl][q];
        const float as = asl[cc], ad = adl[cc];
        if (loc < thr0) { s0 += a * as; d0 += a * ad; }
        else            { s1 += a * as; d1 += a * ad; }
      }
      #pragma unroll
      for (int s = 1; s <= 8; s <<= 1) {
        s0 += __shfl_xor(s0, s); s1 += __shfl_xor(s1, s);
        d0 += __shfl_xor(d0, s); d1 += __shfl_xor(d1, s);
      }
      if (r == 0) {
        const int row_l = mt * 16 + g * 4 + q;
        sp0[w][row_l] = s0; sp1[w][row_l] = s1;
        dp0[w][row_l] = d0; dp1[w][row_l] = d1;
      }
    }
  }
  __syncthreads();
  if (t < 256) {
    const int hd = t >> 5, row_l = t & 31;
    s1g[((size_t)b * 8 + hd) * 128 + row0 + row_l] = sp0[hd][row_l] + (hd > 0 ? sp1[hd-1][row_l] : 0.f);
    d1g[((size_t)b * 8 + hd) * 128 + row0 + row_l] = dp0[hd][row_l] + (hd > 0 ? dp1[hd-1][row_l] : 0.f);
  }
}

// ===== merged attention-fragment generator (shared by att1/att2) =====
__device__ __forceinline__ float make_att_frags(
    const float si, const u64 ma, const u64 mb2, const float* darr,
    const int g, bf16x8* pah, bf16x8* pal)
{
  const unsigned int mby[4] = {
    (unsigned int)(ma  >> (g * 8)) & 0xffu,
    (unsigned int)(ma  >> (32 + g * 8)) & 0xffu,
    (unsigned int)(mb2 >> (g * 8)) & 0xffu,
    (unsigned int)(mb2 >> (32 + g * 8)) & 0xffu };
  float ev[4][8];
  float mx = -3e38f;
  #pragma unroll
  for (int kt = 0; kt < 4; ++kt)
    #pragma unroll
    for (int e = 0; e < 8; ++e) {
      const int j = ((kt & 1) * 32) + ((kt >> 1) * 64) + g * 8 + e;
      float v = si + darr[j];
      v = fmaxf(v, LRA * v);
      const float vv = (mby[((kt & 1) << 1) | (kt >> 1)] & (1u << e)) ? v : -3e38f;
      ev[kt][e] = vv;
      mx = fmaxf(mx, vv);
    }
  mx = fmaxf(mx, __shfl_xor(mx, 16));
  mx = fmaxf(mx, __shfl_xor(mx, 32));
  float sum = 0.f;
  #pragma unroll
  for (int kt = 0; kt < 4; ++kt)
    #pragma unroll
    for (int e = 0; e < 8; ++e) {
      const float p = (ev[kt][e] > -1e37f) ? __expf(ev[kt][e] - mx) : 0.f;
      ev[kt][e] = p;
      sum += p;
    }
  sum += __shfl_xor(sum, 16);
  sum += __shfl_xor(sum, 32);
  #pragma unroll
  for (int kt = 0; kt < 4; ++kt) {
    const int ks = ((kt & 1) << 1) | (kt >> 1);
    union { unsigned int u[4]; bf16x8 v; } hw, lw;
    #pragma unroll
    for (int p2 = 0; p2 < 4; ++p2) {
      const float p0 = ev[ks][2 * p2], p1 = ev[ks][2 * p2 + 1];
      const unsigned short h0 = f2bf(p0), h1 = f2bf(p1);
      hw.u[p2] = h0 | ((unsigned int)h1 << 16);
      lw.u[p2] = f2bf(p0 - bf2f(h0)) | ((unsigned int)f2bf(p1 - bf2f(h1)) << 16);
    }
    pah[kt] = hw.v;
    pal[kt] = lw.v;
  }
  return 1.f / sum;
}

// =============== att1: per (b,head); h = elu(att@Wh) in-place ===============
__global__ __launch_bounds__(256) void k_att1(
    unsigned int* __restrict__ buf1, const u64* __restrict__ mg,
    const float* __restrict__ s1g, const float* __restrict__ d1g)
{
  __shared__ unsigned short Th[16][64][8], Tl[16][64][8];
  __shared__ float sarr[128], darr[128];
  __shared__ u64 mAr[128], mBr[128];
  const int t = threadIdx.x, lane = t & 63, w = t >> 6, r = lane & 15, g = lane >> 4;
  const int bid = blockIdx.x;
  const int lb = ((bid & 7) << 9) | (bid >> 3);
  const int b = lb >> 3, hd = lb & 7;
  const size_t sl = (size_t)b * 8 + hd;
  unsigned int* slab = buf1 + sl * 7680;

  if (t < 128) {
    sarr[t] = s1g[sl * 128 + t];
    darr[t] = d1g[sl * 128 + t];
    mAr[t] = mg[((size_t)b * 128 + t) * 2];
    mBr[t] = mg[((size_t)b * 128 + t) * 2 + 1];
  }
  #pragma unroll
  for (int ii = 0; ii < 4; ++ii) {
    const int idx = t + ii * 256;
    const int c = idx & 63, jg = idx >> 6;
    uint4 p0 = {0,0,0,0}, p1 = {0,0,0,0};
    if (c < 60) {
      const uint4* src = (const uint4*)&slab[(size_t)c * 128 + jg * 8];
      p0 = src[0]; p1 = src[1];
    }
    const unsigned int pw[8] = {p0.x,p0.y,p0.z,p0.w,p1.x,p1.y,p1.z,p1.w};
    u16x8 hv, lv;
    #pragma unroll
    for (int e = 0; e < 8; ++e) { hv[e] = (unsigned short)(pw[e] >> 16); lv[e] = (unsigned short)(pw[e] & 0xffffu); }
    const int tile = ((c >> 4) << 2) | (jg >> 2);
    const int li = ((jg & 3) << 4) | (c & 15);
    *(u16x8*)&Th[tile][li][0] = hv;
    *(u16x8*)&Tl[tile][li][0] = lv;
  }
  __syncthreads();
  bf16x8 pah[2][4], pal[2][4];
  float inv2[2];
  #pragma unroll
  for (int mt = 0; mt < 2; ++mt) {
    const int i = w * 32 + mt * 16 + r;
    inv2[mt] = make_att_frags(sarr[i], mAr[i], mBr[i], darr, g, pah[mt], pal[mt]);
  }
  f32x4 acc[2][4];
  #pragma unroll
  for (int mt = 0; mt < 2; ++mt)
    #pragma unroll
    for (int nt = 0; nt < 4; ++nt) acc[mt][nt] = (f32x4){0.f,0.f,0.f,0.f};
  #pragma unroll
  for (int kt = 0; kt < 4; ++kt)
    #pragma unroll
    for (int nt = 0; nt < 4; ++nt) {
      const bf16x8 bh = *(const bf16x8*)&Th[(nt << 2) | kt][lane][0];
      const bf16x8 bl = *(const bf16x8*)&Tl[(nt << 2) | kt][lane][0];
      #pragma unroll
      for (int mt = 0; mt < 2; ++mt) {
        acc[mt][nt] = __builtin_amdgcn_mfma_f32_16x16x32_bf16(pah[mt][kt], bh, acc[mt][nt], 0,0,0);
        acc[mt][nt] = __builtin_amdgcn_mfma_f32_16x16x32_bf16(pal[mt][kt], bh, acc[mt][nt], 0,0,0);
        acc[mt][nt] = __builtin_amdgcn_mfma_f32_16x16x32_bf16(pah[mt][kt], bl, acc[mt][nt], 0,0,0);
      }
    }
  #pragma unroll
  for (int mt = 0; mt < 2; ++mt) {
    float sc[4];
    #pragma unroll
    for (int q = 0; q < 4; ++q) sc[q] = __shfl(inv2[mt], g * 4 + q);
    #pragma unroll
    for (int nt = 0; nt < 4; ++nt) {
      const int cc = nt * 16 + r;
      if (cc < 60) {
        #pragma unroll
        for (int q = 0; q < 4; ++q) {
          const int row = w * 32 + mt * 16 + g * 4 + q;
          float v = acc[mt][nt][q] * sc[q];
          v = v > 0.f ? v : __expf(v) - 1.f;
          const unsigned short h = f2bf(v), l = f2bf(v - bf2f(h));
          slab[(size_t)row * 60 + cc] = ((unsigned int)h << 16) | l;
        }
      }
    }
  }
}

// =============== GEMM2: Wo = h @ W_out; 2 row-parts (64 rows) per batch ===============
// grid 1024: b = bid>>1, p = bid&1 (rows p*64..). 4 waves, wave w: nt w*5..w*5+4.
// acc[4][5] = 80 VGPR; launch_bounds(256,3).
__global__ __launch_bounds__(256, 3) void k_gemm2(
    unsigned int* __restrict__ buf1,
    const unsigned short* __restrict__ BH, const unsigned short* __restrict__ BL,
    const float* __restrict__ aos, const float* __restrict__ aod,
    float* __restrict__ s2g, float* __restrict__ d2g)
{
  __shared__ unsigned int Apk[64][32];
  __shared__ float aosl[320], aodl[320];
  __shared__ float sred[4][64], dred[4][64];
  const int t = threadIdx.x, lane = t & 63, w = t >> 6, r = lane & 15, g = lane >> 4;
  const int b = blockIdx.x >> 1, p = blockIdx.x & 1;
  const int row0 = p * 64;
  unsigned int* slab = buf1 + (size_t)b * 61440;
  if (t < 320) { aosl[t] = t < 300 ? aos[t] : 0.f; aodl[t] = t < 300 ? aod[t] : 0.f; }

  f32x4 acc[4][5];
  #pragma unroll
  for (int mt = 0; mt < 4; ++mt)
    #pragma unroll
    for (int ntl = 0; ntl < 5; ++ntl) acc[mt][ntl] = (f32x4){0.f,0.f,0.f,0.f};

  for (int kt = 0; kt < 15; ++kt) {
    #pragma unroll
    for (int i = 0; i < 2; ++i) {
      const int idx = t + i * 256, row_l = idx >> 3, sl = idx & 7;
      const int k0 = kt * 32 + sl * 4;
      const int hd = k0 / 60, c = k0 - hd * 60;   // 4-quad never crosses head boundary
      const uint4 v = *(const uint4*)&slab[(size_t)hd * 7680 + (size_t)(row0 + row_l) * 60 + c];
      *(uint4*)&Apk[row_l][((sl ^ (row_l & 7)) << 2)] = v;
    }
    bf16x8 bh[5], bl[5];
    #pragma unroll
    for (int ntl = 0; ntl < 5; ++ntl) {
      const int nt = w * 5 + ntl;
      const size_t off = (((size_t)(kt * 20 + nt)) * 64 + lane) * 8;
      bh[ntl] = *(const bf16x8*)&BH[off];
      bl[ntl] = *(const bf16x8*)&BL[off];
    }
    __syncthreads();
    #pragma unroll
    for (int mt = 0; mt < 4; ++mt) {
      const int row_l = mt * 16 + r, key = r & 7;
      const uint4 p0 = *(const uint4*)&Apk[row_l][(((2*g)   ^ key) << 2)];
      const uint4 p1 = *(const uint4*)&Apk[row_l][(((2*g+1) ^ key) << 2)];
      const unsigned int pw[8] = {p0.x,p0.y,p0.z,p0.w,p1.x,p1.y,p1.z,p1.w};
      bf16x8 ah, al;
      #pragma unroll
      for (int e = 0; e < 8; ++e) { ah[e] = (short)(pw[e] >> 16); al[e] = (short)(pw[e] & 0xffffu); }
      #pragma unroll
      for (int ntl = 0; ntl < 5; ++ntl) {
        acc[mt][ntl] = __builtin_amdgcn_mfma_f32_16x16x32_bf16(ah, bh[ntl], acc[mt][ntl], 0,0,0);
        acc[mt][ntl] = __builtin_amdgcn_mfma_f32_16x16x32_bf16(al, bh[ntl], acc[mt][ntl], 0,0,0);
        acc[mt][ntl] = __builtin_amdgcn_mfma_f32_16x16x32_bf16(ah, bl[ntl], acc[mt][ntl], 0,0,0);
      }
    }
    __syncthreads();
  }
  // WoT packed store (rows of this part)
  #pragma unroll
  for (int mt = 0; mt < 4; ++mt)
    #pragma unroll
    for (int ntl = 0; ntl < 5; ++ntl) {
      const int cc = w * 80 + ntl * 16 + r;
      if (cc < 300) {
        uint4 pv;
        unsigned int* pp = (unsigned int*)&pv;
        #pragma unroll
        for (int q = 0; q < 4; ++q) {
          const float v = acc[mt][ntl][q];
          const unsigned short h = f2bf(v);
          pp[q] = ((unsigned int)h << 16) | f2bf(v - bf2f(h));
        }
        *(uint4*)&slab[(size_t)cc * 128 + row0 + mt * 16 + (g << 2)] = pv;
      }
    }
  // s2/d2 per-wave partials, cross-wave sum (rows local)
  #pragma unroll
  for (int mt = 0; mt < 4; ++mt) {
    #pragma unroll
    for (int q = 0; q < 4; ++q) {
      float sv = 0.f, dv = 0.f;
      #pragma unroll
      for (int ntl = 0; ntl < 5; ++ntl) {
        const int cc = w * 80 + ntl * 16 + r;
        const float a = acc[mt][ntl][q];
        sv += a * aosl[cc]; dv += a * aodl[cc];
      }
      #pragma unroll
      for (int s = 1; s <= 8; s <<= 1) { sv += __shfl_xor(sv, s); dv += __shfl_xor(dv, s); }
      if (r == 0) {
        const int row_l = mt * 16 + g * 4 + q;
        sred[w][row_l] = sv; dred[w][row_l] = dv;
      }
    }
  }
  __syncthreads();
  if (t < 64) {
    s2g[(size_t)b * 128 + row0 + t] = sred[0][t] + sred[1][t] + sred[2][t] + sred[3][t];
    d2g[(size_t)b * 128 + row0 + t] = dred[0][t] + dred[1][t] + dred[2][t] + dred[3][t];
  }
}

// =============== att2 + elu + log_softmax(features) + mean (rank-1) ===============
__global__ __launch_bounds__(256) void k_att2(
    const unsigned int* __restrict__ buf1, const u64* __restrict__ mg,
    const float* __restrict__ s2g, const float* __restrict__ d2g,
    float* __restrict__ gat)
{
  __shared__ unsigned short Th[16][64][8], Tl[16][64][8];
  __shared__ float sarr[128], darr[128];
  __shared__ u64 mAr[128], mBr[128];
  __shared__ float colsum[304];
  __shared__ float srow[16];
  const int t = threadIdx.x, lane = t & 63, w = t >> 6, r = lane & 15, g = lane >> 4;
  const int b = blockIdx.x;
  const unsigned int* slab = buf1 + (size_t)b * 61440;

  if (t < 128) {
    sarr[t] = s2g[(size_t)b * 128 + t];
    darr[t] = d2g[(size_t)b * 128 + t];
    mAr[t] = mg[((size_t)b * 128 + t) * 2];
    mBr[t] = mg[((size_t)b * 128 + t) * 2 + 1];
  }
  for (int c = t; c < 304; c += 256) colsum[c] = 0.f;
  __syncthreads();
  bf16x8 pah[2][4], pal[2][4];
  float inv2[2];
  #pragma unroll
  for (int mt = 0; mt < 2; ++mt) {
    const int i = w * 32 + mt * 16 + r;
    inv2[mt] = make_att_frags(sarr[i], mAr[i], mBr[i], darr, g, pah[mt], pal[mt]);
  }
  float scq[2][4];
  #pragma unroll
  for (int mt = 0; mt < 2; ++mt)
    #pragma unroll
    for (int q = 0; q < 4; ++q) scq[mt][q] = __shfl(inv2[mt], g * 4 + q);

  float m8[2][4], l8[2][4];
  #pragma unroll
  for (int mt = 0; mt < 2; ++mt)
    #pragma unroll
    for (int q = 0; q < 4; ++q) { m8[mt][q] = -3e38f; l8[mt][q] = 0.f; }

  for (int ch = 0; ch < 5; ++ch) {
    #pragma unroll
    for (int ii = 0; ii < 4; ++ii) {
      const int idx = t + ii * 256;
      const int c = idx & 63, jg = idx >> 6;
      const int gc = ch * 64 + c;
      uint4 p0 = {0,0,0,0}, p1 = {0,0,0,0};
      if (gc < 300) {
        const uint4* src = (const uint4*)&slab[(size_t)gc * 128 + jg * 8];
        p0 = src[0]; p1 = src[1];
      }
      const unsigned int pw[8] = {p0.x,p0.y,p0.z,p0.w,p1.x,p1.y,p1.z,p1.w};
      u16x8 hv, lv;
      #pragma unroll
      for (int e = 0; e < 8; ++e) { hv[e] = (unsigned short)(pw[e] >> 16); lv[e] = (unsigned short)(pw[e] & 0xffffu); }
      const int tile = ((c >> 4) << 2) | (jg >> 2);
      const int li = ((jg & 3) << 4) | (c & 15);
      *(u16x8*)&Th[tile][li][0] = hv;
      *(u16x8*)&Tl[tile][li][0] = lv;
    }
    __syncthreads();
    f32x4 pacc[2][4];
    #pragma unroll
    for (int mt = 0; mt < 2; ++mt)
      #pragma unroll
      for (int nt = 0; nt < 4; ++nt) pacc[mt][nt] = (f32x4){0.f,0.f,0.f,0.f};
    #pragma unroll
    for (int kt = 0; kt < 4; ++kt)
      #pragma unroll
      for (int nt = 0; nt < 4; ++nt) {
        const bf16x8 bh = *(const bf16x8*)&Th[(nt << 2) | kt][lane][0];
        const bf16x8 bl = *(const bf16x8*)&Tl[(nt << 2) | kt][lane][0];
        #pragma unroll
        for (int mt = 0; mt < 2; ++mt) {
          pacc[mt][nt] = __builtin_amdgcn_mfma_f32_16x16x32_bf16(pah[mt][kt], bh, pacc[mt][nt], 0,0,0);
          pacc[mt][nt] = __builtin_amdgcn_mfma_f32_16x16x32_bf16(pal[mt][kt], bh, pacc[mt][nt], 0,0,0);
          pacc[mt][nt] = __builtin_amdgcn_mfma_f32_16x16x32_bf16(pah[mt][kt], bl, pacc[mt][nt], 0,0,0);
        }
      }
    float csA[4] = {0,0,0,0};
    #pragma unroll
    for (int mt = 0; mt < 2; ++mt) {
      float vq[4][4];
      #pragma unroll
      for (int nt = 0; nt < 4; ++nt) {
        const int cc = ch * 64 + nt * 16 + r;
        const bool cv = cc < 300;
        #pragma unroll
        for (int q = 0; q < 4; ++q) {
          float v = pacc[mt][nt][q] * scq[mt][q];
          v = v > 0.f ? v : __expf(v) - 1.f;
          vq[nt][q] = cv ? v : -3e38f;
          csA[nt] += cv ? v : 0.f;
        }
      }
      #pragma unroll
      for (int q = 0; q < 4; ++q) {
        float mx = fmaxf(fmaxf(vq[0][q], vq[1][q]), fmaxf(vq[2][q], vq[3][q]));
        mx = fmaxf(mx, __shfl_xor(mx, 1));
        mx = fmaxf(mx, __shfl_xor(mx, 2));
        mx = fmaxf(mx, __shfl_xor(mx, 4));
        mx = fmaxf(mx, __shfl_xor(mx, 8));
        const float nm = fmaxf(m8[mt][q], mx);
        float ps = __expf(vq[0][q]-nm) + __expf(vq[1][q]-nm) + __expf(vq[2][q]-nm) + __expf(vq[3][q]-nm);
        ps += __shfl_xor(ps, 1); ps += __shfl_xor(ps, 2);
        ps += __shfl_xor(ps, 4); ps += __shfl_xor(ps, 8);
        l8[mt][q] = l8[mt][q] * __expf(m8[mt][q] - nm) + ps;
        m8[mt][q] = nm;
      }
    }
    #pragma unroll
    for (int nt = 0; nt < 4; ++nt) {
      float cs = csA[nt];
      cs += __shfl_xor(cs, 16); cs += __shfl_xor(cs, 32);
      const int cc = ch * 64 + nt * 16 + r;
      if (g == 0 && cc < 300) atomicAdd(&colsum[cc], cs);
    }
    __syncthreads();
  }
  if (r == 0) {
    float sp = 0.f;
    #pragma unroll
    for (int mt = 0; mt < 2; ++mt)
      #pragma unroll
      for (int q = 0; q < 4; ++q) sp += m8[mt][q] + __logf(l8[mt][q]);
    srow[w * 4 + g] = sp;
  }
  __syncthreads();
  float S = 0.f;
  #pragma unroll
  for (int k = 0; k < 16; ++k) S += srow[k];
  for (int c = t; c < 300; c += 256)
    gat[(size_t)b * 300 + c] = (colsum[c] - S) * (1.f / 128.f);
}

// =============== split-K GEMM: P[sk][M][N] = A_chunk @ B_chunk (64x64 tile) ===============
__global__ __launch_bounds__(256) void k_gemm_sk(
    const float* __restrict__ A, const float* __restrict__ B,
    float* __restrict__ P, int M, int K, int N, int kpt)
{
  __shared__ unsigned short Ah[64][40], Al[64][40], Bh[64][40], Bl[64][40];
  const int t = threadIdx.x, lane = t & 63, w = t >> 6, r = lane & 15, g = lane >> 4;
  const int row0 = blockIdx.x * 64, col0 = blockIdx.y * 64;
  const int sk = blockIdx.z;
  const int k0 = sk * kpt * 32;
  const int kend = min(K, k0 + kpt * 32);

  f32x4 acc[4];
  #pragma unroll
  for (int nt = 0; nt < 4; ++nt) acc[nt] = (f32x4){0.f,0.f,0.f,0.f};

  for (int kt = k0; kt < kend; kt += 32) {
    #pragma unroll
    for (int ii = 0; ii < 2; ++ii) {
      const int idx = t + ii * 256, ar = idx >> 3, aq = (idx & 7) * 4, gk = kt + aq;
      const float* ap = &A[(size_t)(row0 + ar) * K + gk];
      float v0 = gk     < kend ? ap[0] : 0.f;
      float v1 = gk + 1 < kend ? ap[1] : 0.f;
      float v2 = gk + 2 < kend ? ap[2] : 0.f;
      float v3 = gk + 3 < kend ? ap[3] : 0.f;
      unsigned short h0=f2bf(v0),h1=f2bf(v1),h2=f2bf(v2),h3=f2bf(v3);
      *(unsigned int*)&Ah[ar][aq]   = h0 | ((unsigned int)h1 << 16);
      *(unsigned int*)&Ah[ar][aq+2] = h2 | ((unsigned int)h3 << 16);
      unsigned short l0=f2bf(v0-bf2f(h0)),l1=f2bf(v1-bf2f(h1)),l2=f2bf(v2-bf2f(h2)),l3=f2bf(v3-bf2f(h3));
      *(unsigned int*)&Al[ar][aq]   = l0 | ((unsigned int)l1 << 16);
      *(unsigned int*)&Al[ar][aq+2] = l2 | ((unsigned int)l3 << 16);
    }
    #pragma unroll
    for (int ii = 0; ii < 4; ++ii) {
      const int idx = t + ii * 256, n = idx & 63, kk = (idx >> 6) * 2;
      const int gn = col0 + n;
      float v0 = (gn < N && kt + kk     < kend) ? B[(size_t)(kt + kk) * N + gn] : 0.f;
      float v1 = (gn < N && kt + kk + 1 < kend) ? B[(size_t)(kt + kk + 1) * N + gn] : 0.f;
      unsigned short h0 = f2bf(v0), h1 = f2bf(v1);
      *(unsigned int*)&Bh[n][kk] = h0 | ((unsigned int)h1 << 16);
      unsigned short l0 = f2bf(v0 - bf2f(h0)), l1 = f2bf(v1 - bf2f(h1));
      *(unsigned int*)&Bl[n][kk] = l0 | ((unsigned int)l1 << 16);
    }
    __syncthreads();
    const bf16x8 ah  = *(const bf16x8*)&Ah[w * 16 + r][g * 8];
    const bf16x8 al2 = *(const bf16x8*)&Al[w * 16 + r][g * 8];
    #pragma unroll
    for (int nt = 0; nt < 4; ++nt) {
      const bf16x8 bh = *(const bf16x8*)&Bh[nt * 16 + r][g * 8];
      const bf16x8 bl = *(const bf16x8*)&Bl[nt * 16 + r][g * 8];
      acc[nt] = __builtin_amdgcn_mfma_f32_16x16x32_bf16(ah,  bh, acc[nt], 0,0,0);
      acc[nt] = __builtin_amdgcn_mfma_f32_16x16x32_bf16(al2, bh, acc[nt], 0,0,0);
      acc[nt] = __builtin_amdgcn_mfma_f32_16x16x32_bf16(ah,  bl, acc[nt], 0,0,0);
    }
    __syncthreads();
  }
  float* Pout = P + (size_t)sk * M * N;
  #pragma unroll
  for (int nt = 0; nt < 4; ++nt) {
    const int cc = col0 + nt * 16 + r;
    if (cc < N) {
      #pragma unroll
      for (int q = 0; q < 4; ++q)
        Pout[(size_t)(row0 + w * 16 + g * 4 + q) * N + cc] = acc[nt][q];
    }
  }
}

// =============== split-K reduce + bias + activation ===============
__global__ __launch_bounds__(256) void k_reduce(
    const float* __restrict__ P, const float* __restrict__ bias,
    float* __restrict__ C, int M, int N, int ldc, int nsk, int act)
{
  const int idx = blockIdx.x * 256 + threadIdx.x;
  if (idx >= M * N) return;
  const int row = idx / N, col = idx - row * N;
  float s = bias[col];
  for (int k = 0; k < nsk; ++k) s += P[(size_t)k * M * N + idx];
  if (act) s = fmaxf(s, 0.f);
  C[(size_t)row * ldc + col] = s;
}

// =============== final GEMV + sigmoid ===============
__global__ __launch_bounds__(512) void k_out(
    const float* __restrict__ z1, const float* __restrict__ w2,
    const float* __restrict__ b2, float* __restrict__ out)
{
  const int t = threadIdx.x, lane = t & 63, w = t >> 6;
  const int b = blockIdx.x * 8 + w;
  float p = 0.f;
  for (int k = lane; k < 300; k += 64) p += z1[(size_t)b * 300 + k] * w2[k];
  p = warp_sum(p);
  if (lane == 0) out[b] = 1.f / (1.f + __expf(-(p + b2[0])));
}

extern "C" void kernel_launch(void* const* d_in, const int* in_sizes, int n_in,
                              void* d_out, int out_size, void* d_ws, size_t ws_size,
                              hipStream_t stream)
{
  const float* x    = (const float*)d_in[0];
  const int*   adj  = (const int*)d_in[1];
  const float* fp   = (const float*)d_in[2];
  const float* Whw  = (const float*)d_in[3];
  const float* asrc = (const float*)d_in[4];
  const float* adst = (const float*)d_in[5];
  const float* Wout = (const float*)d_in[6];
  const float* aos  = (const float*)d_in[7];
  const float* aod  = (const float*)d_in[8];
  const float* fc1w = (const float*)d_in[9];
  const float* fc1b = (const float*)d_in[10];
  const float* fc2w = (const float*)d_in[11];
  const float* fc2b = (const float*)d_in[12];
  const float* fcgw = (const float*)d_in[13];
  const float* fcgb = (const float*)d_in[14];
  const float* fcfw = (const float*)d_in[15];
  const float* fcfb = (const float*)d_in[16];
  const float* f1w  = (const float*)d_in[17];
  const float* f1b  = (const float*)d_in[18];
  const float* f2w  = (const float*)d_in[19];
  const float* f2b  = (const float*)d_in[20];
  float* out = (float*)d_out;

  char* wsb = (char*)d_ws;
  unsigned int* buf1 = (unsigned int*)wsb;
  float* s1g = (float*)(wsb + 125829120);
  float* d1g = (float*)(wsb + 127926272);
  float* s2g = (float*)(wsb + 130023424);
  float* d2g = (float*)(wsb + 130285568);
  u64*   mgb = (u64*)  (wsb + 130547712);
  float* gatp = (float*)(wsb + 131596288);
  float* fpnp = (float*)(wsb + 132210688);
  float* f1buf = (float*)(wsb + 132825088);
  float* zb    = (float*)(wsb + 133873664);
  float* z1b   = (float*)(wsb + 135102464);
  float* P0 = (float*)(wsb + 135716864);
  float* P1 = (float*)(wsb + 142008320);
  float* P2 = (float*)(wsb + 144465920);
  float* P3 = (float*)(wsb + 145694720);
  float* P4 = (float*)(wsb + 146923520);
  unsigned short* Bf1H = (unsigned short*)(wsb + 149381120);
  unsigned short* Bf1L = (unsigned short*)(wsb + 149544960);
  unsigned short* Bf2H = (unsigned short*)(wsb + 149708800);
  unsigned short* Bf2L = (unsigned short*)(wsb + 150016000);

  k_prep1<<<dim3(5, 32), 64, 0, stream>>>(Whw, Bf1H, Bf1L);
  k_prep2<<<dim3(15, 20), 64, 0, stream>>>(Wout, Bf2H, Bf2L);
  k_mask <<<512, 256, 0, stream>>>(adj, mgb);
  k_gemm1<<<2048, 512, 0, stream>>>(x, Bf1H, Bf1L, asrc, adst, buf1, s1g, d1g);
  k_att1 <<<4096, 256, 0, stream>>>(buf1, mgb, s1g, d1g);
  k_gemm2<<<1024, 256, 0, stream>>>(buf1, Bf2H, Bf2L, aos, aod, s2g, d2g);
  k_att2 <<<512, 256, 0, stream>>>(buf1, mgb, s2g, d2g, gatp);
  k_gemm_sk<<<dim3(8,8,6), 256, 0, stream>>>(fp, fc1w, P0, 512, 1489, 512, 8);
  k_reduce<<<1024, 256, 0, stream>>>(P0, fc1b, f1buf, 512, 512, 512, 6, 1);
  k_gemm_sk<<<dim3(8,5,4), 256, 0, stream>>>(f1buf, fc2w, P1, 512, 512, 300, 4);
  k_reduce<<<600, 256, 0, stream>>>(P1, fc2b, fpnp, 512, 300, 300, 4, 0);
  k_gemm_sk<<<dim3(8,5,2), 256, 0, stream>>>(gatp, fcgw, P2, 512, 300, 300, 5);
  k_gemm_sk<<<dim3(8,5,2), 256, 0, stream>>>(fpnp, fcfw, P3, 512, 300, 300, 5);
  k_reduce<<<600, 256, 0, stream>>>(P2, fcgb, zb, 512, 300, 600, 2, 1);
  k_reduce<<<600, 256, 0, stream>>>(P3, fcfb, zb + 300, 512, 300, 600, 2, 1);
  k_gemm_sk<<<dim3(8,5,4), 256, 0, stream>>>(zb, f1w, P4, 512, 600, 300, 5);
  k_reduce<<<600, 256, 0, stream>>>(P4, f1b, z1b, 512, 300, 300, 4, 1);
  k_out<<<64, 512, 0, stream>>>(z1b, f2w, f2b, out);
}